// Round 1
// 498.554 us; speedup vs baseline: 1.0210x; 1.0210x over previous
//
#include <hip/hip_runtime.h>

// Pipeline (R13: dis-prescaling folded into producer epilogues so the agg
// inner loop is a pure unweighted gather-add; conv0 agg moved BEFORE its
// matmul (agg(h)@W == agg(h@W)) so it gathers 64-wide rows, not 128):
//   A  = relu([x|st]@W1+b1)                 [N,128] mm1  (fp32 VALU)
//   h0 = bf16(dis*relu(A@W2+b2))            [N,64]  mm2  (fp32 VALU, dis-scaled)
//   a0 = bf16(dis[d]*(sum h0[s] + h0[d]))   [N,64]  agg0 (unweighted gather)
//   h1 = bf16(relu(a0@Wg0 + bg0))           [N,128] mmx3 (MFMA, bias+relu)
//   P  = bf16(dis*(h1@Wg1))                 [N,128] mmx4 (MFMA, dis-scaled)
//   h2 = bf16(relu(dis[d]*(sum+self)+bg1))  [N,128] agg1
//   Q  = bf16(dis*(h2@Wg2))                 [N,64]  mmx5 (MFMA, dis-scaled)
//   out= dis[d]*(sum+self)+bg2              [N,64]  agg2 -> d_out (fp32)
//
// Math: out[d] = dis[d]*(sum_s dis[s]*P[s] + dis[d]*P[d]); with P'[i]=dis[i]*P[i]
// this is dis[d]*(sum_s P'[s] + P'[d]) -- per-edge weights vanish.
// MFMA layouts (guide-verified): A[m=lane&15][k=(lane>>4)*8+j], B mirrored,
// C/D[row=(lane>>4)*4+reg][col=lane&15].

__device__ __forceinline__ unsigned short bf16rne(float f) {
    unsigned u = __float_as_uint(f);
    unsigned r = (u + 0x7fffu + ((u >> 16) & 1u)) >> 16;
    return (unsigned short)r;
}
__device__ __forceinline__ float bf16lo(unsigned v) { return __uint_as_float(v << 16); }
__device__ __forceinline__ float bf16hi(unsigned v) { return __uint_as_float(v & 0xffff0000u); }

using bf16x8 = __attribute__((ext_vector_type(8))) short;
using f32x4  = __attribute__((ext_vector_type(4))) float;

// ---------------- graph preprocessing: bucketed CSR (dst>>8 buckets) --------

__global__ __launch_bounds__(256) void k_hist(const int* __restrict__ dst, int e, int nb,
                                              int* __restrict__ gh) {
    __shared__ int h[512];
    const int t = threadIdx.x;
    h[t] = 0; h[t + 256] = 0;
    __syncthreads();
    const int base = blockIdx.x * 4096;
    const int end = min(base + 4096, e);
    for (int i = base + t; i < end; i += 256) atomicAdd(&h[dst[i] >> 8], 1);
    __syncthreads();
    for (int b = t; b < nb; b += 256)
        if (h[b]) atomicAdd(&gh[b], h[b]);
}

__global__ __launch_bounds__(512) void k_scan(const int* __restrict__ gh, int nb, int e, int n,
                                              int* __restrict__ bbase, int* __restrict__ gcur,
                                              int* __restrict__ offs) {
    __shared__ int sm[512];
    const int t = threadIdx.x;
    int v = (t < nb) ? gh[t] : 0;
    sm[t] = v;
    __syncthreads();
    for (int off = 1; off < 512; off <<= 1) {
        int add = (t >= off) ? sm[t - off] : 0;
        __syncthreads();
        sm[t] += add;
        __syncthreads();
    }
    if (t < nb) {
        int excl = sm[t] - v;
        bbase[t] = excl;
        gcur[t] = excl;
    }
    if (t == 0) { bbase[nb] = e; offs[n] = e; }
}

__global__ __launch_bounds__(256) void k_scatter1(const int* __restrict__ src,
                                                  const int* __restrict__ dst, int e, int nb,
                                                  int* __restrict__ gcur,
                                                  int2* __restrict__ ep) {
    __shared__ int h[512];
    __shared__ int cbase[512];
    const int t = threadIdx.x;
    h[t] = 0; h[t + 256] = 0;
    __syncthreads();
    const int base = blockIdx.x * 4096;
    const int end = min(base + 4096, e);
    for (int i = base + t; i < end; i += 256) atomicAdd(&h[dst[i] >> 8], 1);
    __syncthreads();
    for (int b = t; b < nb; b += 256) {
        int c = h[b];
        cbase[b] = c ? atomicAdd(&gcur[b], c) : 0;
        h[b] = 0;
    }
    __syncthreads();
    for (int i = base + t; i < end; i += 256) {
        int d = dst[i];
        int bn = d >> 8;
        int r = atomicAdd(&h[bn], 1);
        ep[cbase[bn] + r] = make_int2(src[i], d);
    }
}

__global__ __launch_bounds__(256) void k_build(const int2* __restrict__ ep,
                                               const int* __restrict__ bbase, int n,
                                               int* __restrict__ offs,
                                               int* __restrict__ ssrc,
                                               float* __restrict__ dis) {
    __shared__ int cnt[256];
    __shared__ int sm[256];
    __shared__ int cur[256];
    const int t = threadIdx.x;
    const int b = blockIdx.x;
    const int lo = bbase[b];
    const int hi = bbase[b + 1];
    cnt[t] = 0;
    __syncthreads();
    for (int i = lo + t; i < hi; i += 256) atomicAdd(&cnt[ep[i].y & 255], 1);
    __syncthreads();
    int v = cnt[t];
    sm[t] = v;
    __syncthreads();
    for (int off = 1; off < 256; off <<= 1) {
        int add = (t >= off) ? sm[t - off] : 0;
        __syncthreads();
        sm[t] += add;
        __syncthreads();
    }
    const int excl = sm[t] - v;
    const int node = (b << 8) + t;
    if (node < n) {
        offs[node] = lo + excl;
        dis[node] = rsqrtf(1.0f + (float)v);
    }
    cur[t] = lo + excl;
    __syncthreads();
    for (int i = lo + t; i < hi; i += 256) {
        int2 p = ep[i];
        int pos = atomicAdd(&cur[p.y & 255], 1);
        ssrc[pos] = p.x;
    }
}

__global__ __launch_bounds__(256) void k_sort(const int* __restrict__ offs,
                                              int* __restrict__ ssrc, int n) {
    const int wv = threadIdx.x >> 6;
    const int lane = threadIdx.x & 63;
    const int node = blockIdx.x * 4 + wv;
    if (node >= n) return;
    const int jb = offs[node];
    const int je = offs[node + 1];
    const int len = je - jb;
    if (len <= 1) return;
    if (len <= 64) {
        int v = (lane < len) ? ssrc[jb + lane] : 0x7fffffff;
#pragma unroll
        for (int k = 2; k <= 64; k <<= 1) {
            for (int j = k >> 1; j > 0; j >>= 1) {
                int p = __shfl_xor(v, j);
                bool lower = (lane & j) == 0;
                bool asc = (lane & k) == 0;
                v = (lower == asc) ? min(v, p) : max(v, p);
            }
        }
        if (lane < len) ssrc[jb + lane] = v;
    } else if (lane == 0) {
        for (int a = jb + 1; a < je; a++) {
            int key = ssrc[a];
            int b = a - 1;
            while (b >= jb && ssrc[b] > key) { ssrc[b + 1] = ssrc[b]; b--; }
            ssrc[b + 1] = key;
        }
    }
}

// ---------------- W -> MFMA fragment-ordered bf16 ---------------------------
// Wf[((kt*CT+ct)*64+lane)*8 + j] = bf16(W[kt*32+(lane>>4)*8+j][ct*16+(lane&15)])
// One thread per bf16 element: grid must cover K*FOUT threads.

__global__ void k_wprep(const float* __restrict__ W, unsigned short* __restrict__ Wf,
                        int K, int FOUT) {
    const int CT = FOUT / 16;
    int tid = blockIdx.x * 256 + threadIdx.x;
    int total = K * FOUT;
    if (tid >= total) return;
    int j = tid & 7;
    int lane = (tid >> 3) & 63;
    int ct = (tid >> 9) % CT;
    int kt = tid / (512 * CT);
    int k = kt * 32 + (lane >> 4) * 8 + j;
    int c = ct * 16 + (lane & 15);
    Wf[tid] = bf16rne(W[(size_t)k * FOUT + c]);
}

// ---------------- MFMA matmul: out[n,FOUT](bf16) = in[n,K](bf16) @ Wf -------
// Block = 64 nodes (4 waves x 16 rows). Wave computes 16 x FOUT via CT
// col-tiles of mfma_f32_16x16x32_bf16, KT = K/32 k-steps.
// BR: fused +bias, relu (conv0 post-agg). SCALE: fused *dis[row] (pre-agg).

template <int K, int FOUT, bool BR, bool SCALE>
__global__ __launch_bounds__(256) void k_mmx(const unsigned short* __restrict__ in,
                                             const unsigned short* __restrict__ Wf,
                                             const float* __restrict__ bias,
                                             const float* __restrict__ dis,
                                             unsigned short* __restrict__ out, int n) {
    constexpr int KT = K / 32;
    constexpr int CT = FOUT / 16;
    const int t = threadIdx.x;
    const int wv = t >> 6;
    const int lane = t & 63;
    const int rowBase = blockIdx.x * 64 + wv * 16;
    const int m = lane & 15;
    const int q = lane >> 4;

    f32x4 acc[CT];
#pragma unroll
    for (int c = 0; c < CT; c++) acc[c] = (f32x4){0.f, 0.f, 0.f, 0.f};

    int arow = rowBase + m;
    if (arow >= n) arow = n - 1;
    const unsigned short* ap = in + (size_t)arow * K + q * 8;
    const bf16x8* wfp = (const bf16x8*)Wf;

#pragma unroll
    for (int kt = 0; kt < KT; kt++) {
        bf16x8 a = *(const bf16x8*)(ap + kt * 32);
#pragma unroll
        for (int c = 0; c < CT; c++) {
            bf16x8 b = wfp[(kt * CT + c) * 64 + lane];
            acc[c] = __builtin_amdgcn_mfma_f32_16x16x32_bf16(a, b, acc[c], 0, 0, 0);
        }
    }

    float bv[CT];
    if constexpr (BR) {
#pragma unroll
        for (int c = 0; c < CT; c++) bv[c] = bias[c * 16 + m];
    }

    // D[row=(lane>>4)*4+r][col=lane&15] per col-tile
    const int crow = rowBase + q * 4;
#pragma unroll
    for (int r = 0; r < 4; r++) {
        int rr = crow + r;
        if (rr >= n) continue;
        float sc = 1.f;
        if constexpr (SCALE) sc = dis[rr];
#pragma unroll
        for (int c = 0; c < CT; c++) {
            float v = acc[c][r];
            if constexpr (SCALE) v *= sc;
            if constexpr (BR) v = fmaxf(v + bv[c], 0.f);
            out[(size_t)rr * FOUT + c * 16 + m] = bf16rne(v);
        }
    }
}

// ---------------- dense matmul (fp32 VALU, MLP only) ------------------------

template <int FIN1, int FIN2, int FOUT, bool BIAS, bool RELU, bool OBF16, bool SCALE>
__global__ __launch_bounds__(256) void k_mm(const float* __restrict__ in1,
                                            const float* __restrict__ in2,
                                            const float* __restrict__ W,
                                            const float* __restrict__ bias,
                                            const float* __restrict__ dis,
                                            void* __restrict__ outv, int n) {
    constexpr int FINT = FIN1 + FIN2;
    constexpr int ROWF = FINT + 4;
    constexpr int JPT = FOUT / 4;
    constexpr int NC4 = JPT / 4;

    __shared__ float lds[64 * ROWF];

    const int t = threadIdx.x;
    const int base = blockIdx.x * 64;

    {
        constexpr int R4 = FIN1 / 4;
        const float4* g = (const float4*)in1;
        for (int i = t; i < 64 * R4; i += 256) {
            int r = i / R4, c = i % R4;
            float4 v = (base + r < n) ? g[(size_t)(base + r) * R4 + c]
                                      : make_float4(0.f, 0.f, 0.f, 0.f);
            *(float4*)&lds[r * ROWF + c * 4] = v;
        }
    }
    if constexpr (FIN2 > 0) {
        constexpr int R4 = FIN2 / 4;
        const float4* g = (const float4*)in2;
        for (int i = t; i < 64 * R4; i += 256) {
            int r = i / R4, c = i % R4;
            float4 v = (base + r < n) ? g[(size_t)(base + r) * R4 + c]
                                      : make_float4(0.f, 0.f, 0.f, 0.f);
            *(float4*)&lds[r * ROWF + FIN1 + c * 4] = v;
        }
    }
    __syncthreads();

    const int lane = t & 63;
    const int f0 = __builtin_amdgcn_readfirstlane((t >> 6) * JPT);

    float4 c0, c1, c2, c3, c4, c5, c6, c7;
    if (BIAS) {
        const float4* b4 = (const float4*)(bias + f0);
        c0 = b4[0]; c1 = b4[1]; c2 = b4[2]; c3 = b4[3];
        if (NC4 == 8) { c4 = b4[4]; c5 = b4[5]; c6 = b4[6]; c7 = b4[7]; }
        else { c4 = c5 = c6 = c7 = make_float4(0.f, 0.f, 0.f, 0.f); }
    } else {
        c0 = c1 = c2 = c3 = c4 = c5 = c6 = c7 = make_float4(0.f, 0.f, 0.f, 0.f);
    }

#define FMA_BLK(av, wp)                                                                              \
    do {                                                                                             \
        const float4* _w4 = (const float4*)(wp);                                                     \
        { float4 _t = _w4[0]; c0.x = fmaf(av, _t.x, c0.x); c0.y = fmaf(av, _t.y, c0.y);              \
          c0.z = fmaf(av, _t.z, c0.z); c0.w = fmaf(av, _t.w, c0.w); }                                \
        { float4 _t = _w4[1]; c1.x = fmaf(av, _t.x, c1.x); c1.y = fmaf(av, _t.y, c1.y);              \
          c1.z = fmaf(av, _t.z, c1.z); c1.w = fmaf(av, _t.w, c1.w); }                                \
        { float4 _t = _w4[2]; c2.x = fmaf(av, _t.x, c2.x); c2.y = fmaf(av, _t.y, c2.y);              \
          c2.z = fmaf(av, _t.z, c2.z); c2.w = fmaf(av, _t.w, c2.w); }                                \
        { float4 _t = _w4[3]; c3.x = fmaf(av, _t.x, c3.x); c3.y = fmaf(av, _t.y, c3.y);              \
          c3.z = fmaf(av, _t.z, c3.z); c3.w = fmaf(av, _t.w, c3.w); }                                \
        if constexpr (NC4 == 8) {                                                                    \
            { float4 _t = _w4[4]; c4.x = fmaf(av, _t.x, c4.x); c4.y = fmaf(av, _t.y, c4.y);          \
              c4.z = fmaf(av, _t.z, c4.z); c4.w = fmaf(av, _t.w, c4.w); }                            \
            { float4 _t = _w4[5]; c5.x = fmaf(av, _t.x, c5.x); c5.y = fmaf(av, _t.y, c5.y);          \
              c5.z = fmaf(av, _t.z, c5.z); c5.w = fmaf(av, _t.w, c5.w); }                            \
            { float4 _t = _w4[6]; c6.x = fmaf(av, _t.x, c6.x); c6.y = fmaf(av, _t.y, c6.y);          \
              c6.z = fmaf(av, _t.z, c6.z); c6.w = fmaf(av, _t.w, c6.w); }                            \
            { float4 _t = _w4[7]; c7.x = fmaf(av, _t.x, c7.x); c7.y = fmaf(av, _t.y, c7.y);          \
              c7.z = fmaf(av, _t.z, c7.z); c7.w = fmaf(av, _t.w, c7.w); }                            \
        }                                                                                            \
    } while (0)

    const float* arow = &lds[lane * ROWF];
    for (int k = 0; k < FINT; k += 4) {
        float4 a = *(const float4*)(arow + k);
        const float* wr = W + (size_t)k * FOUT + f0;
        FMA_BLK(a.x, wr);
        FMA_BLK(a.y, wr + FOUT);
        FMA_BLK(a.z, wr + 2 * FOUT);
        FMA_BLK(a.w, wr + 3 * FOUT);
    }
#undef FMA_BLK

    const int node = base + lane;
    if (node < n) {
        if (RELU) {
#define RL(c) do { c.x = fmaxf(c.x, 0.f); c.y = fmaxf(c.y, 0.f); \
                   c.z = fmaxf(c.z, 0.f); c.w = fmaxf(c.w, 0.f); } while (0)
            RL(c0); RL(c1); RL(c2); RL(c3);
            if (NC4 == 8) { RL(c4); RL(c5); RL(c6); RL(c7); }
#undef RL
        }
        if constexpr (SCALE) {
            const float sc = dis[node];
#define SC(c) do { c.x *= sc; c.y *= sc; c.z *= sc; c.w *= sc; } while (0)
            SC(c0); SC(c1); SC(c2); SC(c3);
            if (NC4 == 8) { SC(c4); SC(c5); SC(c6); SC(c7); }
#undef SC
        }
        if constexpr (OBF16) {
            unsigned short* orow = (unsigned short*)outv + (size_t)node * FOUT + f0;
#define ST4(i, c)                                                                  \
            do {                                                                   \
                ushort4 r;                                                         \
                r.x = bf16rne(c.x); r.y = bf16rne(c.y);                            \
                r.z = bf16rne(c.z); r.w = bf16rne(c.w);                            \
                *(ushort4*)(orow + (i) * 4) = r;                                   \
            } while (0)
            ST4(0, c0); ST4(1, c1); ST4(2, c2); ST4(3, c3);
            if (NC4 == 8) { ST4(4, c4); ST4(5, c5); ST4(6, c6); ST4(7, c7); }
#undef ST4
        } else {
            float4* orow = (float4*)((float*)outv + (size_t)node * FOUT + f0);
            orow[0] = c0; orow[1] = c1; orow[2] = c2; orow[3] = c3;
            if (NC4 == 8) { orow[4] = c4; orow[5] = c5; orow[6] = c6; orow[7] = c7; }
        }
    }
}

// ---------------- GCN aggregation (bf16 rows, half-wave pairing) ------------
// Inputs are dis-prescaled (P'[i] = dis[i]*P[i]) so the inner loop is a pure
// unweighted gather-add; dis[node] is applied once in the epilogue:
//   v = dis[node]*(sum_nb + self) [+ bias] [relu]
// OB: output bf16 (intermediates) else fp32 (final).

template <int F, bool RELU, bool OB, bool BIAS>
__global__ __launch_bounds__(256) void k_agg(const unsigned short* __restrict__ hW,
                                             const float* __restrict__ bias,
                                             const float* __restrict__ dis,
                                             const int* __restrict__ offs,
                                             const int* __restrict__ ssrc,
                                             void* __restrict__ outv, int n) {
    constexpr int FPL = F / 32;
    const int wv = threadIdx.x >> 6;
    const int lane = threadIdx.x & 63;
    const int node = blockIdx.x * 4 + wv;
    if (node >= n) return;
    const int g = lane >> 5;
    const int hl = lane & 31;
    const int jb = offs[node];
    const int je = offs[node + 1];

    float a0 = 0.f, a1 = 0.f, a2 = 0.f, a3 = 0.f;
    const unsigned short* lbase = hW + hl * FPL;

#define ROW_ADD(sidx)                                                               \
    do {                                                                            \
        if constexpr (FPL == 4) {                                                   \
            uint2 rv = *(const uint2*)(lbase + (size_t)(sidx) * F);                 \
            a0 += bf16lo(rv.x);                                                     \
            a1 += bf16hi(rv.x);                                                     \
            a2 += bf16lo(rv.y);                                                     \
            a3 += bf16hi(rv.y);                                                     \
        } else {                                                                    \
            unsigned rv = *(const unsigned*)(lbase + (size_t)(sidx) * F);           \
            a0 += bf16lo(rv);                                                       \
            a1 += bf16hi(rv);                                                       \
        }                                                                           \
    } while (0)

    int j = jb;
    for (; j + 8 <= je; j += 8) {
        int sv = ssrc[j + (lane & 7)];
        int s0 = __shfl(sv, 0 + g);
        int s1 = __shfl(sv, 2 + g);
        int s2 = __shfl(sv, 4 + g);
        int s3 = __shfl(sv, 6 + g);
        ROW_ADD(s0);
        ROW_ADD(s1);
        ROW_ADD(s2);
        ROW_ADD(s3);
    }
    for (; j + 2 <= je; j += 2) {
        int s = ssrc[j + g];
        ROW_ADD(s);
    }
    if (j < je) {
        int st = ssrc[j];
        if (g == 0) ROW_ADD(st);
    }
#undef ROW_ADD

    a0 += __shfl_xor(a0, 32);
    a1 += __shfl_xor(a1, 32);
    if constexpr (FPL == 4) {
        a2 += __shfl_xor(a2, 32);
        a3 += __shfl_xor(a3, 32);
    }

    if (g == 0) {
        const float di = dis[node];
        if constexpr (FPL == 4) {
            uint2 sv = *(const uint2*)(hW + (size_t)node * F + hl * 4);
            float v0 = (a0 + bf16lo(sv.x)) * di;
            float v1 = (a1 + bf16hi(sv.x)) * di;
            float v2 = (a2 + bf16lo(sv.y)) * di;
            float v3 = (a3 + bf16hi(sv.y)) * di;
            if constexpr (BIAS) {
                float4 bb = *(const float4*)(bias + hl * 4);
                v0 += bb.x; v1 += bb.y; v2 += bb.z; v3 += bb.w;
            }
            if (RELU) {
                v0 = fmaxf(v0, 0.f); v1 = fmaxf(v1, 0.f);
                v2 = fmaxf(v2, 0.f); v3 = fmaxf(v3, 0.f);
            }
            if constexpr (OB) {
                ushort4 o;
                o.x = bf16rne(v0); o.y = bf16rne(v1);
                o.z = bf16rne(v2); o.w = bf16rne(v3);
                *(ushort4*)((unsigned short*)outv + (size_t)node * F + hl * 4) = o;
            } else {
                *(float4*)((float*)outv + (size_t)node * F + hl * 4) =
                    make_float4(v0, v1, v2, v3);
            }
        } else {
            unsigned sv = *(const unsigned*)(hW + (size_t)node * F + hl * 2);
            float v0 = (a0 + bf16lo(sv)) * di;
            float v1 = (a1 + bf16hi(sv)) * di;
            if constexpr (BIAS) {
                float2 bb = *(const float2*)(bias + hl * 2);
                v0 += bb.x; v1 += bb.y;
            }
            if (RELU) { v0 = fmaxf(v0, 0.f); v1 = fmaxf(v1, 0.f); }
            if constexpr (OB) {
                ushort2 o;
                o.x = bf16rne(v0); o.y = bf16rne(v1);
                *(ushort2*)((unsigned short*)outv + (size_t)node * F + hl * 2) = o;
            } else {
                *(float2*)((float*)outv + (size_t)node * F + hl * 2) =
                    make_float2(v0, v1);
            }
        }
    }
}

// ---------------- launch -----------------------------------------------------

extern "C" void kernel_launch(void* const* d_in, const int* in_sizes, int n_in,
                              void* d_out, int out_size, void* d_ws, size_t ws_size,
                              hipStream_t stream) {
    const float* x   = (const float*)d_in[0];
    const float* st  = (const float*)d_in[1];
    const int*   src = (const int*)d_in[2];
    const int*   dst = (const int*)d_in[3];
    const float* W1  = (const float*)d_in[4];
    const float* b1  = (const float*)d_in[5];
    const float* W2  = (const float*)d_in[6];
    const float* b2  = (const float*)d_in[7];
    const float* Wg0 = (const float*)d_in[8];
    const float* bg0 = (const float*)d_in[9];
    const float* Wg1 = (const float*)d_in[10];
    const float* bg1 = (const float*)d_in[11];
    const float* Wg2 = (const float*)d_in[12];
    const float* bg2 = (const float*)d_in[13];

    const int n = in_sizes[0] / 64;  // IN_DIM = 64
    const int e = in_sizes[2];
    const int nb = (n + 255) >> 8;

    char* wp = (char*)d_ws;
    auto carve = [&](size_t bytes) {
        void* p = (void*)wp;
        wp += (bytes + 255) & ~(size_t)255;
        return p;
    };
    int*   ghist = (int*)carve(512 * 4);
    int*   gcur  = (int*)carve(512 * 4);
    int*   bbase = (int*)carve(513 * 4);
    int*   offs  = (int*)carve((size_t)(n + 1) * 4);
    float* dis   = (float*)carve((size_t)n * 4);
    int*   ssrc  = (int*)carve((size_t)e * 4);
    char*  R3    = (char*)carve((size_t)n * 128 * 4);  // ep -> M1 -> h1|h2
    char*  R2    = (char*)carve((size_t)n * 64 * 2);   // h0 -> Q
    unsigned short* W0f = (unsigned short*)carve((size_t)64 * 128 * 2);
    unsigned short* W1f = (unsigned short*)carve((size_t)128 * 128 * 2);
    unsigned short* W2f = (unsigned short*)carve((size_t)128 * 64 * 2);

    // aliases (stream-ordered lifetimes):
    int2* ep = (int2*)R3;                                 // dead after k_build
    float* M1 = (float*)R3;                               // mm1 out, dead after mm2
    unsigned short* h1 = (unsigned short*)R3;             // mmx3 out (n*128 bf16)
    unsigned short* h2 = (unsigned short*)(R3 + (size_t)n * 128 * 2);  // agg1 out
    unsigned short* h0 = (unsigned short*)R2;             // mm2 out (dis-scaled)
    unsigned short* Q  = (unsigned short*)R2;             // mmx5 out (dis-scaled)
    unsigned short* a0 = (unsigned short*)d_out;          // agg0 out (n*64 bf16)
    unsigned short* P  = (unsigned short*)d_out;          // mmx4 out (n*128 bf16)

    hipMemsetAsync(ghist, 0, 512 * 4, stream);

    const int gN64 = (n + 63) / 64;
    const int gAgg = (n + 3) / 4;
    const int gE4k = (e + 4095) / 4096;

    // graph prep
    k_hist<<<gE4k, 256, 0, stream>>>(dst, e, nb, ghist);
    k_scan<<<1, 512, 0, stream>>>(ghist, nb, e, n, bbase, gcur, offs);
    k_scatter1<<<gE4k, 256, 0, stream>>>(src, dst, e, nb, gcur, ep);
    k_build<<<nb, 256, 0, stream>>>(ep, bbase, n, offs, ssrc, dis);
    k_sort<<<gAgg, 256, 0, stream>>>(offs, ssrc, n);

    // W fragment prep: one thread per bf16 element = K*FOUT threads
    k_wprep<<<(64 * 128 + 255) / 256, 256, 0, stream>>>(Wg0, W0f, 64, 128);
    k_wprep<<<(128 * 128 + 255) / 256, 256, 0, stream>>>(Wg1, W1f, 128, 128);
    k_wprep<<<(128 * 64 + 255) / 256, 256, 0, stream>>>(Wg2, W2f, 128, 64);

    // MLP (fp32 VALU); mm2 output is dis-prescaled for agg0
    k_mm<64, 32, 128, true, true, false, false><<<gN64, 256, 0, stream>>>(
        x, st, W1, b1, nullptr, M1, n);
    k_mm<128, 0, 64, true, true, true, true><<<gN64, 256, 0, stream>>>(
        M1, nullptr, W2, b2, dis, h0, n);

    // conv0: agg FIRST at F=64 (agg(h)@W == agg(h@W)), then MFMA w/ bias+relu
    k_agg<64, false, true, false><<<gAgg, 256, 0, stream>>>(h0, nullptr, dis, offs, ssrc, a0, n);
    k_mmx<64, 128, true, false><<<gN64, 256, 0, stream>>>(a0, W0f, bg0, nullptr, h1, n);

    // conv1: MFMA mm (dis-prescaled) -> agg@128 (dis+bias+relu, bf16 out)
    k_mmx<128, 128, false, true><<<gN64, 256, 0, stream>>>(h1, W1f, nullptr, dis, P, n);
    k_agg<128, true, true, true><<<gAgg, 256, 0, stream>>>(P, bg1, dis, offs, ssrc, h2, n);

    // conv2: MFMA mm (dis-prescaled) -> agg@64 (dis+bias, fp32 out) -> d_out
    k_mmx<128, 64, false, true><<<gN64, 256, 0, stream>>>(h2, W2f, nullptr, dis, Q, n);
    k_agg<64, false, false, true><<<gAgg, 256, 0, stream>>>(Q, bg2, dis, offs, ssrc,
                                                            (float*)d_out, n);
}